// Round 1
// baseline (371.437 us; speedup 1.0000x reference)
//
#include <hip/hip_runtime.h>
#include <hip/hip_bf16.h>
#include <cstdint>
#include <cstddef>

// MoE: T=4096 tokens, D=1024, H=2816, E=8 experts, top-K=2, SwiGLU.
// Strategy: fp32 gate (selection must match np ref), sparse routing,
// bf16 MFMA FFN (threshold is 2% of max|ref| -> bf16 is fine).

#define Tt 4096
#define Dd 1024
#define Hh 2816
#define Ee 8

typedef __bf16 bf16_t;
typedef __bf16 bf16x8 __attribute__((ext_vector_type(8)));
typedef float f32x4 __attribute__((ext_vector_type(4)));

__device__ __forceinline__ void gload16(const void* g, void* l) {
  __builtin_amdgcn_global_load_lds(
      (__attribute__((address_space(1))) void*)(void*)(uintptr_t)g,
      (__attribute__((address_space(3))) void*)l, 16, 0, 0);
}

// ---------------- gate: fp32 logits, top-2, softmax, atomic routing ---------
__global__ __launch_bounds__(256) void gate_kernel(
    const float* __restrict__ x, const float* __restrict__ gw_g,
    int* __restrict__ counts, int* __restrict__ perm, float* __restrict__ topkw) {
  __shared__ float gw[Dd * 9];  // pitch 9 to spread banks
  const int tid = threadIdx.x;
  for (int i = tid; i < Dd * Ee; i += 256) gw[(i >> 3) * 9 + (i & 7)] = gw_g[i];
  __syncthreads();
  const int tok = blockIdx.x * 32 + (tid >> 3);
  const int part = tid & 7;
  const float* xr = x + (size_t)tok * Dd;
  float acc[Ee];
#pragma unroll
  for (int e = 0; e < Ee; ++e) acc[e] = 0.f;
  for (int i = 0; i < 32; ++i) {
    const int d = i * 32 + part * 4;
    const float4 xv = *(const float4*)(xr + d);
    const float xs[4] = {xv.x, xv.y, xv.z, xv.w};
#pragma unroll
    for (int j = 0; j < 4; ++j)
#pragma unroll
      for (int e = 0; e < Ee; ++e) acc[e] += xs[j] * gw[(d + j) * 9 + e];
  }
#pragma unroll
  for (int s = 1; s < 8; s <<= 1)
#pragma unroll
    for (int e = 0; e < Ee; ++e) acc[e] += __shfl_xor(acc[e], s, 64);
  if (part == 0) {
    int i0 = 0; float v0 = acc[0];
#pragma unroll
    for (int e = 1; e < Ee; ++e) if (acc[e] > v0) { v0 = acc[e]; i0 = e; }
    int i1 = -1; float v1 = -1e30f;
#pragma unroll
    for (int e = 0; e < Ee; ++e)
      if (e != i0 && acc[e] > v1) { v1 = acc[e]; i1 = e; }
    const float w0 = 1.f / (1.f + __expf(v1 - v0));
    topkw[tok * 2 + 0] = w0;
    topkw[tok * 2 + 1] = 1.f - w0;
    const int p0 = atomicAdd(&counts[i0], 1);
    perm[i0 * Tt + p0] = tok * 2 + 0;
    const int p1 = atomicAdd(&counts[i1], 1);
    perm[i1 * Tt + p1] = tok * 2 + 1;
  }
}

__global__ void scan_kernel(const int* __restrict__ counts, int* __restrict__ offs) {
  if (threadIdx.x == 0) {
    int s = 0;
    for (int e = 0; e < Ee; ++e) { offs[e] = s; s += counts[e]; }
    offs[Ee] = s;
  }
}

// ---------------- cast x -> bf16 -------------------------------------------
__global__ __launch_bounds__(256) void cast_x_kernel(const float* __restrict__ x,
                                                     bf16_t* __restrict__ xb) {
  const size_t idx = ((size_t)blockIdx.x * 256 + threadIdx.x) * 8;
  const float4 a = *(const float4*)(x + idx);
  const float4 b = *(const float4*)(x + idx + 4);
  bf16x8 v;
  v[0] = (__bf16)a.x; v[1] = (__bf16)a.y; v[2] = (__bf16)a.z; v[3] = (__bf16)a.w;
  v[4] = (__bf16)b.x; v[5] = (__bf16)b.y; v[6] = (__bf16)b.z; v[7] = (__bf16)b.w;
  *(bf16x8*)(xb + idx) = v;
}

// ---------------- transpose + cast weights to bf16 (k-contiguous) ----------
// w1,w3: [E][D][H] fp32 -> [E][H][D] bf16 ; w2: [E][H][D] fp32 -> [E][D][H] bf16
__global__ __launch_bounds__(256) void prep_w_kernel(
    const float* __restrict__ w1, const float* __restrict__ w3,
    const float* __restrict__ w2, bf16_t* __restrict__ w1t,
    bf16_t* __restrict__ w3t, bf16_t* __restrict__ w2t) {
  int bid = blockIdx.x;
  const int ntile = Ee * (Dd / 64) * (Hh / 64);  // 5632
  const float* src; bf16_t* dst; int R, C;
  if (bid < ntile) { src = w1; dst = w1t; R = Dd; C = Hh; }
  else if (bid < 2 * ntile) { src = w3; dst = w3t; R = Dd; C = Hh; bid -= ntile; }
  else { src = w2; dst = w2t; R = Hh; C = Dd; bid -= 2 * ntile; }
  const int tilesC = C / 64, tilesR = R / 64;
  const int e = bid / (tilesR * tilesC);
  const int rem = bid % (tilesR * tilesC);
  const int r0 = (rem / tilesC) * 64, c0 = (rem % tilesC) * 64;
  src += (size_t)e * R * C;
  dst += (size_t)e * R * C;

  __shared__ bf16_t tile[64 * 68];
  const int tid = threadIdx.x;
#pragma unroll
  for (int i = 0; i < 16; ++i) {
    const int r = (tid >> 6) + i * 4;
    const int c = tid & 63;
    tile[c * 68 + r] = (__bf16)src[(size_t)(r0 + r) * C + c0 + c];
  }
  __syncthreads();
#pragma unroll
  for (int i = 0; i < 4; ++i) {
    const int c = i * 16 + (tid >> 4);
    const int rch = (tid & 15) * 4;
    uint2 val;
    val.x = *(const uint32_t*)(tile + c * 68 + rch);
    val.y = *(const uint32_t*)(tile + c * 68 + rch + 2);
    *(uint2*)(dst + (size_t)(c0 + c) * R + r0 + rch) = val;
  }
}

// ---------------- FFN part 1: h = silu(X@W1) * (X@W3) ----------------------
// 128x128 tile, BK=64, 4 waves (2x2), 16x16x32 bf16 MFMA, swizzled glds.
__global__ __launch_bounds__(256, 2) void ffn1_kernel(
    const bf16_t* __restrict__ xb, const bf16_t* __restrict__ w1t,
    const bf16_t* __restrict__ w3t, const int* __restrict__ perm,
    const int* __restrict__ counts, const int* __restrict__ offs,
    bf16_t* __restrict__ hbuf) {
  const int e = blockIdx.z;
  const int ne = counts[e];
  const int m0 = blockIdx.y * 128;
  if (m0 >= ne) return;
  const int h0 = blockIdx.x * 128;

  __shared__ __align__(16) bf16_t As[128 * 64];
  __shared__ __align__(16) bf16_t B1s[128 * 64];
  __shared__ __align__(16) bf16_t B3s[128 * 64];

  const int tid = threadIdx.x;
  const int lane = tid & 63;
  const int wid = tid >> 6;

  // staging: chunk c = i*256+tid -> LDS row c>>3, 16B chunk (c&7).
  // XOR swizzle s(row)=(row&7)<<3 on element col, applied to the SOURCE.
  const int scol = ((tid & 7) << 3) ^ (((tid >> 3) & 7) << 3);
  uint32_t aoff[4], boff[4];
#pragma unroll
  for (int i = 0; i < 4; ++i) {
    const int row = i * 32 + (tid >> 3);
    const int gr = m0 + row;
    const int rec = (gr < ne) ? perm[e * Tt + gr] : 0;
    aoff[i] = (uint32_t)((rec >> 1) * Dd + scol);
    boff[i] = (uint32_t)((h0 + row) * Dd + scol);
  }
  const bf16_t* w1e = w1t + (size_t)e * Hh * Dd;
  const bf16_t* w3e = w3t + (size_t)e * Hh * Dd;

  f32x4 acc1[4][4], acc3[4][4];
#pragma unroll
  for (int m = 0; m < 4; ++m)
#pragma unroll
    for (int n = 0; n < 4; ++n) {
      acc1[m][n] = (f32x4){0.f, 0.f, 0.f, 0.f};
      acc3[m][n] = (f32x4){0.f, 0.f, 0.f, 0.f};
    }

  const int wm = wid >> 1, wn = wid & 1;
  int aoffm[4], boffn[4], koff[2];
#pragma unroll
  for (int m = 0; m < 4; ++m) aoffm[m] = (wm * 64 + m * 16 + (lane & 15)) * 64;
#pragma unroll
  for (int n = 0; n < 4; ++n) boffn[n] = (wn * 64 + n * 16 + (lane & 15)) * 64;
#pragma unroll
  for (int kk = 0; kk < 2; ++kk)
    koff[kk] = (kk * 32 + (lane >> 4) * 8) ^ ((lane & 7) << 3);

  for (int kt = 0; kt < Dd / 64; ++kt) {
    const int d0 = kt * 64;
    __syncthreads();
#pragma unroll
    for (int i = 0; i < 4; ++i) {
      const int lb = (i * 256 + wid * 64) * 8;
      gload16(xb + aoff[i] + d0, As + lb);
      gload16(w1e + boff[i] + d0, B1s + lb);
      gload16(w3e + boff[i] + d0, B3s + lb);
    }
    asm volatile("s_waitcnt vmcnt(0)" ::: "memory");
    __syncthreads();
#pragma unroll
    for (int kk = 0; kk < 2; ++kk) {
      bf16x8 a[4], b1[4], b3[4];
#pragma unroll
      for (int m = 0; m < 4; ++m) a[m] = *(const bf16x8*)(As + aoffm[m] + koff[kk]);
#pragma unroll
      for (int n = 0; n < 4; ++n) {
        b1[n] = *(const bf16x8*)(B1s + boffn[n] + koff[kk]);
        b3[n] = *(const bf16x8*)(B3s + boffn[n] + koff[kk]);
      }
#pragma unroll
      for (int m = 0; m < 4; ++m)
#pragma unroll
        for (int n = 0; n < 4; ++n) {
          acc1[m][n] = __builtin_amdgcn_mfma_f32_16x16x32_bf16(a[m], b1[n], acc1[m][n], 0, 0, 0);
          acc3[m][n] = __builtin_amdgcn_mfma_f32_16x16x32_bf16(a[m], b3[n], acc3[m][n], 0, 0, 0);
        }
    }
  }

  const int hb = offs[e];
#pragma unroll
  for (int m = 0; m < 4; ++m) {
    const int rb = m0 + wm * 64 + m * 16 + ((lane >> 4) << 2);
#pragma unroll
    for (int r = 0; r < 4; ++r) {
      const int gr = rb + r;
      if (gr >= ne) continue;
      bf16_t* orow = hbuf + (size_t)(hb + gr) * Hh + h0 + wn * 64 + (lane & 15);
#pragma unroll
      for (int n = 0; n < 4; ++n) {
        const float v1 = acc1[m][n][r];
        const float v3 = acc3[m][n][r];
        const float s = v1 / (1.f + __expf(-v1));
        orow[n * 16] = (__bf16)(s * v3);
      }
    }
  }
}

// ---------------- FFN part 2: o = (h @ W2) * w_slot, scatter to slot buffer -
__global__ __launch_bounds__(256, 2) void ffn2_kernel(
    const bf16_t* __restrict__ hbuf, const bf16_t* __restrict__ w2t,
    const int* __restrict__ perm, const int* __restrict__ counts,
    const int* __restrict__ offs, const float* __restrict__ topkw,
    float* __restrict__ obuf) {
  const int e = blockIdx.z;
  const int ne = counts[e];
  const int m0 = blockIdx.y * 128;
  if (m0 >= ne) return;
  const int n0 = blockIdx.x * 128;

  __shared__ __align__(16) bf16_t As[128 * 64];
  __shared__ __align__(16) bf16_t Bs[128 * 64];

  const int tid = threadIdx.x;
  const int lane = tid & 63;
  const int wid = tid >> 6;
  const int hb = offs[e];

  const int scol = ((tid & 7) << 3) ^ (((tid >> 3) & 7) << 3);
  uint32_t aoff[4], boff[4];
#pragma unroll
  for (int i = 0; i < 4; ++i) {
    const int row = i * 32 + (tid >> 3);
    int ar = hb + m0 + row;
    if (ar > 2 * Tt - 1) ar = 2 * Tt - 1;
    aoff[i] = (uint32_t)(ar * Hh + scol);
    boff[i] = (uint32_t)((n0 + row) * Hh + scol);
  }
  const bf16_t* w2e = w2t + (size_t)e * Dd * Hh;

  f32x4 acc[4][4];
#pragma unroll
  for (int m = 0; m < 4; ++m)
#pragma unroll
    for (int n = 0; n < 4; ++n) acc[m][n] = (f32x4){0.f, 0.f, 0.f, 0.f};

  const int wm = wid >> 1, wn = wid & 1;
  int aoffm[4], boffn[4], koff[2];
#pragma unroll
  for (int m = 0; m < 4; ++m) aoffm[m] = (wm * 64 + m * 16 + (lane & 15)) * 64;
#pragma unroll
  for (int n = 0; n < 4; ++n) boffn[n] = (wn * 64 + n * 16 + (lane & 15)) * 64;
#pragma unroll
  for (int kk = 0; kk < 2; ++kk)
    koff[kk] = (kk * 32 + (lane >> 4) * 8) ^ ((lane & 7) << 3);

  for (int kt = 0; kt < Hh / 64; ++kt) {
    const int k0 = kt * 64;
    __syncthreads();
#pragma unroll
    for (int i = 0; i < 4; ++i) {
      const int lb = (i * 256 + wid * 64) * 8;
      gload16(hbuf + aoff[i] + k0, As + lb);
      gload16(w2e + boff[i] + k0, Bs + lb);
    }
    asm volatile("s_waitcnt vmcnt(0)" ::: "memory");
    __syncthreads();
#pragma unroll
    for (int kk = 0; kk < 2; ++kk) {
      bf16x8 a[4], b[4];
#pragma unroll
      for (int m = 0; m < 4; ++m) a[m] = *(const bf16x8*)(As + aoffm[m] + koff[kk]);
#pragma unroll
      for (int n = 0; n < 4; ++n) b[n] = *(const bf16x8*)(Bs + boffn[n] + koff[kk]);
#pragma unroll
      for (int m = 0; m < 4; ++m)
#pragma unroll
        for (int n = 0; n < 4; ++n)
          acc[m][n] = __builtin_amdgcn_mfma_f32_16x16x32_bf16(a[m], b[n], acc[m][n], 0, 0, 0);
    }
  }

#pragma unroll
  for (int m = 0; m < 4; ++m) {
    const int rb = m0 + wm * 64 + m * 16 + ((lane >> 4) << 2);
#pragma unroll
    for (int r = 0; r < 4; ++r) {
      const int gr = rb + r;
      if (gr >= ne) continue;
      const int rec = perm[e * Tt + gr];
      const float wgt = topkw[rec];
      float* orow = obuf + (size_t)rec * Dd + n0 + wn * 64 + (lane & 15);
#pragma unroll
      for (int n = 0; n < 4; ++n) orow[n * 16] = wgt * acc[m][n][r];
    }
  }
}

// ---------------- combine: out[t] = obuf[2t] + obuf[2t+1] -------------------
__global__ __launch_bounds__(256) void combine_kernel(const float* __restrict__ obuf,
                                                      float* __restrict__ out) {
  const int t = blockIdx.x;
  const int d = threadIdx.x * 4;
  const float4 a = *(const float4*)(obuf + (size_t)(2 * t) * Dd + d);
  const float4 b = *(const float4*)(obuf + (size_t)(2 * t + 1) * Dd + d);
  float4 o;
  o.x = a.x + b.x; o.y = a.y + b.y; o.z = a.z + b.z; o.w = a.w + b.w;
  *(float4*)(out + (size_t)t * Dd + d) = o;
}

extern "C" void kernel_launch(void* const* d_in, const int* in_sizes, int n_in,
                              void* d_out, int out_size, void* d_ws, size_t ws_size,
                              hipStream_t stream) {
  const float* x = (const float*)d_in[0];
  const float* gate_w = (const float*)d_in[1];
  const float* w1 = (const float*)d_in[2];
  const float* w2 = (const float*)d_in[3];
  const float* w3 = (const float*)d_in[4];
  float* out = (float*)d_out;

  char* ws = (char*)d_ws;
  size_t off = 0;
  auto alloc = [&](size_t b) { size_t r = off; off += (b + 255) & ~(size_t)255; return r; };
  float* topkw   = (float*)(ws + alloc((size_t)Tt * 2 * 4));
  int* counts    = (int*)(ws + alloc(Ee * 4));
  int* offs      = (int*)(ws + alloc((Ee + 1) * 4));
  int* perm      = (int*)(ws + alloc((size_t)Ee * Tt * 4));
  bf16_t* xb     = (bf16_t*)(ws + alloc((size_t)Tt * Dd * 2));
  bf16_t* w1t    = (bf16_t*)(ws + alloc((size_t)Ee * Hh * Dd * 2));
  bf16_t* w3t    = (bf16_t*)(ws + alloc((size_t)Ee * Hh * Dd * 2));
  bf16_t* w2t    = (bf16_t*)(ws + alloc((size_t)Ee * Dd * Hh * 2));
  bf16_t* hbuf   = (bf16_t*)(ws + alloc((size_t)Tt * 2 * Hh * 2));
  float* obuf    = (float*)(ws + alloc((size_t)Tt * 2 * Dd * 4));
  if (ws_size < off) return;  // ws too small -> visible clean failure (absmax = max|ref|)

  hipMemsetAsync(counts, 0, Ee * 4, stream);
  gate_kernel<<<Tt / 32, 256, 0, stream>>>(x, gate_w, counts, perm, topkw);
  scan_kernel<<<1, 64, 0, stream>>>(counts, offs);
  cast_x_kernel<<<(Tt * Dd / 8) / 256, 256, 0, stream>>>(x, xb);
  prep_w_kernel<<<3 * Ee * (Dd / 64) * (Hh / 64), 256, 0, stream>>>(w1, w3, w2, w1t, w3t, w2t);
  ffn1_kernel<<<dim3(Hh / 128, Tt / 128, Ee), 256, 0, stream>>>(xb, w1t, w3t, perm, counts, offs, hbuf);
  ffn2_kernel<<<dim3(Dd / 128, Tt / 128, Ee), 256, 0, stream>>>(hbuf, w2t, perm, counts, offs, topkw, obuf);
  combine_kernel<<<Tt, 256, 0, stream>>>(obuf, out);
}